// Round 12
// baseline (378.781 us; speedup 1.0000x reference)
//
#include <hip/hip_runtime.h>
#include <hip/hip_bf16.h>
#include <stdint.h>
#include <type_traits>

// B=16384, IN=1024, H=1024, K = IN+H = 2048
// Gate order: 0=i, 1=f, 2=o, 3=u
// ws: A_bf16 [16384][2048] @ 0 (64 MiB); B_bf16 [4][1024][2048] (j-major = W^T) @ 64 MiB

typedef short bf16x8 __attribute__((ext_vector_type(8)));
typedef unsigned short u16x8 __attribute__((ext_vector_type(8)));
typedef float f32x4 __attribute__((ext_vector_type(4)));

__device__ __forceinline__ unsigned short f2bf(float f) {
    union { float f; uint32_t u; } v; v.f = f;
    uint32_t r = v.u + 0x7FFFu + ((v.u >> 16) & 1u);   // RNE
    return (unsigned short)(r >> 16);
}

__device__ __forceinline__ float fsig(float x) { return 1.0f / (1.0f + __expf(-x)); }
__device__ __forceinline__ float ftanh(float x) { return 2.0f * fsig(2.0f * x) - 1.0f; }

// ---------------- pack A: [input | prev_h] -> bf16 [16384][2048] ----------------
__global__ __launch_bounds__(256) void pack_a_kernel(const float* __restrict__ input,
                                                     const float* __restrict__ prev_h,
                                                     unsigned short* __restrict__ Apk) {
    long idx = (long)blockIdx.x * 256 + threadIdx.x;
    long e0 = idx * 8;
    int b = (int)(e0 >> 11);
    int k = (int)(e0 & 2047);
    const float* src = (k < 1024) ? (input + (size_t)b * 1024 + k)
                                  : (prev_h + (size_t)b * 1024 + (k - 1024));
    float4 lo = *(const float4*)src;
    float4 hi = *(const float4*)(src + 4);
    u16x8 o;
    o[0] = f2bf(lo.x); o[1] = f2bf(lo.y); o[2] = f2bf(lo.z); o[3] = f2bf(lo.w);
    o[4] = f2bf(hi.x); o[5] = f2bf(hi.y); o[6] = f2bf(hi.z); o[7] = f2bf(hi.w);
    *(u16x8*)(Apk + e0) = o;
}

// ---------------- pack B: per-gate W^T (j-major) bf16 [4][1024][2048] ----------------
__global__ __launch_bounds__(256) void pack_b_kernel(
        const float* __restrict__ wxi, const float* __restrict__ wxf,
        const float* __restrict__ wxo, const float* __restrict__ wxu,
        const float* __restrict__ whi, const float* __restrict__ whf,
        const float* __restrict__ who, const float* __restrict__ whu,
        unsigned short* __restrict__ Bpk) {
    int idx = blockIdx.x * 256 + threadIdx.x;
    int g  = idx >> 18;
    int r  = idx & 262143;
    int kc = r >> 10;
    int j  = r & 1023;
    const float* wx = (g == 0) ? wxi : (g == 1) ? wxf : (g == 2) ? wxo : wxu;
    const float* wh = (g == 0) ? whi : (g == 1) ? whf : (g == 2) ? who : whu;
    int k0 = kc * 8;
    const float* src = (k0 < 1024) ? (wx + (size_t)k0 * 1024 + j)
                                   : (wh + (size_t)(k0 - 1024) * 1024 + j);
    u16x8 o;
#pragma unroll
    for (int t = 0; t < 8; ++t) o[t] = f2bf(src[(size_t)t * 1024]);
    *(u16x8*)(Bpk + (((size_t)(g * 1024 + j)) << 11) + k0) = o;
}

// ---------------- fused GEMM + LSTM epilogue (2 blocks/CU for cross-block overlap) ----------------
// grid 2048 = 128 rowTiles x 16 colTiles; block 256 = 4 waves; wave wq owns one
// 16-col quarter x 128 rows x 4 gates -> acc[8][4]; epilogue lane-local.
// Rationale (R2-R11 post-mortems): within one barrier group the LDS unit serves
// all waves round-robin, so read-phase and MFMA-phase alternate in lockstep
// regardless of schedule (9 variants pinned at 40-43% MfmaUtil). m114: separate
// wave groups on one CU overlap pipes fully. So: 72 KiB LDS (3 x 24 KiB BK=32
// buffers) -> TWO independent blocks/CU; block A's MFMA bursts cover block B's
// LDS bursts. Slice body identical to the proven R11 free-run structure.
// vmcnt(6) @ slice t: outstanding = GLL(t+1)x6 + GLL(t+2)x6 -> drains t+1's.

#define GLL(gp, lp) __builtin_amdgcn_global_load_lds( \
        (__attribute__((address_space(1))) void*)(gp), \
        (__attribute__((address_space(3))) void*)(lp), 16, 0, 0)

#define BAR() do { asm volatile("" ::: "memory"); __builtin_amdgcn_s_barrier(); \
                   asm volatile("" ::: "memory"); } while (0)

__global__ __launch_bounds__(256, 2) void lstm_gemm_kernel(
        const unsigned short* __restrict__ Apk,   // [16384][2048]
        const unsigned short* __restrict__ Bpk,   // [4][1024][2048] j-major
        const float* __restrict__ prev_c,
        const float* __restrict__ bi, const float* __restrict__ bf_,
        const float* __restrict__ bo, const float* __restrict__ bu,
        float* __restrict__ out_h, float* __restrict__ out_c) {
    __shared__ __align__(16) unsigned char smem[73728];   // 3 x 24 KiB (A 8K + B 16K)
    const int tid = threadIdx.x;
    const int w = tid >> 6, l = tid & 63;
    const int lr = l & 15, s4 = l >> 4;
    const int wq = w;                                  // col-quarter

    // XCD-aware bijective swizzle (nwg=2048 % 8 == 0); each XCD: 2 colTiles
    const int bid = blockIdx.x;
    const int sw = ((bid & 7) << 8) + (bid >> 3);
    const int tileRow = sw & 127, tileCol = sw >> 7;
    const int rowBase = tileRow * 128;
    const int jBase = tileCol * 64;

    // read-side swizzled slot (involution key = (row>>1)&3 = (lr>>1)&3)
    const int swr = ((s4 ^ ((lr >> 1) & 3)) << 4);

    int aoff[8], boff[4];
#pragma unroll
    for (int m = 0; m < 8; ++m) aoff[m] = (m * 16 + lr) * 64 + swr;
#pragma unroll
    for (int g = 0; g < 4; ++g) boff[g] = 8192 + (g * 64 + wq * 16 + lr) * 64 + swr;

    // staging: thread covers row rloc, slot (tid&3), source pre-swizzled
    const int rloc = tid >> 2;                         // 0..63
    const int sigS = ((tid & 3) ^ ((rloc >> 1) & 3)) * 8;   // element offset
    const unsigned short* aS0 = Apk + (size_t)(rowBase +  0 + rloc) * 2048 + sigS;
    const unsigned short* aS1 = Apk + (size_t)(rowBase + 64 + rloc) * 2048 + sigS;
    const unsigned short* bS0 = Bpk + (((size_t)(0 * 1024 + jBase + rloc)) << 11) + sigS;
    const unsigned short* bS1 = Bpk + (((size_t)(1 * 1024 + jBase + rloc)) << 11) + sigS;
    const unsigned short* bS2 = Bpk + (((size_t)(2 * 1024 + jBase + rloc)) << 11) + sigS;
    const unsigned short* bS3 = Bpk + (((size_t)(3 * 1024 + jBase + rloc)) << 11) + sigS;
    const int wB = w * 1024;

#define STAGE6(T) do { const int _bb = ((T) % 3) * 24576; \
        GLL(aS0 + (size_t)(T) * 32, smem + _bb +     0 + wB); \
        GLL(aS1 + (size_t)(T) * 32, smem + _bb +  4096 + wB); \
        GLL(bS0 + (size_t)(T) * 32, smem + _bb +  8192 + wB); \
        GLL(bS1 + (size_t)(T) * 32, smem + _bb + 12288 + wB); \
        GLL(bS2 + (size_t)(T) * 32, smem + _bb + 16384 + wB); \
        GLL(bS3 + (size_t)(T) * 32, smem + _bb + 20480 + wB); } while (0)

    f32x4 acc[8][4];
    const f32x4 vzero = {0.f, 0.f, 0.f, 0.f};
#pragma unroll
    for (int m = 0; m < 8; ++m)
#pragma unroll
        for (int g = 0; g < 4; ++g) acc[m][g] = vzero;

    // prologue: stage slices 0,1; drain slice-0 loads (leave slice-1 in flight)
    STAGE6(0); STAGE6(1);
    asm volatile("s_waitcnt vmcnt(6)" ::: "memory");
    BAR();

    auto slice = [&](int t, auto vnc, auto stgc) {
        constexpr int VN = decltype(vnc)::value;   // 6 steady; 0 = drain; -1 = none
        constexpr bool STG = decltype(stgc)::value;
        const int bt = (t % 3) * 24576;
        if constexpr (STG) STAGE6(t + 2);
        bf16x8 bv[4], av[8];
#pragma unroll
        for (int g = 0; g < 4; ++g) bv[g] = *(const bf16x8*)(smem + bt + boff[g]);
#pragma unroll
        for (int m = 0; m < 8; ++m) av[m] = *(const bf16x8*)(smem + bt + aoff[m]);
#pragma unroll
        for (int m = 0; m < 8; ++m)
#pragma unroll
            for (int g = 0; g < 4; ++g)
                acc[m][g] = __builtin_amdgcn_mfma_f32_16x16x32_bf16(av[m], bv[g], acc[m][g], 0, 0, 0);
        if constexpr (VN == 6)      asm volatile("s_waitcnt vmcnt(6)" ::: "memory");
        else if constexpr (VN == 0) asm volatile("s_waitcnt vmcnt(0)" ::: "memory");
        if constexpr (VN >= 0) BAR();
    };

    using c6 = std::integral_constant<int, 6>;
    using c0 = std::integral_constant<int, 0>;
    using cm = std::integral_constant<int, -1>;
    using bT = std::integral_constant<bool, true>;
    using bF = std::integral_constant<bool, false>;

#pragma unroll 1
    for (int t = 0; t < 62; ++t) slice(t, c6{}, bT{});   // t=61 stages slice 63
    slice(62, c0{}, bF{});
    slice(63, cm{}, bF{});

    // ---- epilogue: fully lane-local (all 4 gates in-register) ----
    const int colIdx = jBase + wq * 16 + lr;
    const float vbi = bi[colIdx], vbf = bf_[colIdx], vbo = bo[colIdx], vbu = bu[colIdx];
    const int rowB = rowBase + s4 * 4;
#pragma unroll
    for (int m = 0; m < 8; ++m) {
#pragma unroll
        for (int tt = 0; tt < 4; ++tt) {
            const size_t idx = (size_t)(rowB + m * 16 + tt) * 1024 + colIdx;
            float zi = acc[m][0][tt] + vbi;
            float zf = acc[m][1][tt] + vbf;
            float zo = acc[m][2][tt] + vbo;
            float zu = acc[m][3][tt] + vbu;
            float iv = fsig(zi), fv = fsig(zf), ov = fsig(zo), uv = ftanh(zu);
            float cv = fv * prev_c[idx] + iv * uv;
            out_c[idx] = cv;
            out_h[idx] = ov * ftanh(cv);
        }
    }
#undef STAGE6
}

extern "C" void kernel_launch(void* const* d_in, const int* in_sizes, int n_in,
                              void* d_out, int out_size, void* d_ws, size_t ws_size,
                              hipStream_t stream) {
    const float* input  = (const float*)d_in[0];
    const float* prev_h = (const float*)d_in[1];
    const float* prev_c = (const float*)d_in[2];
    const float* wxi = (const float*)d_in[3];
    const float* whi = (const float*)d_in[4];
    const float* wxf = (const float*)d_in[5];
    const float* whf = (const float*)d_in[6];
    const float* wxu = (const float*)d_in[7];
    const float* whu = (const float*)d_in[8];
    const float* wxo = (const float*)d_in[9];
    const float* who = (const float*)d_in[10];
    const float* bi  = (const float*)d_in[11];
    const float* bf_ = (const float*)d_in[12];
    const float* bo  = (const float*)d_in[13];
    const float* bu  = (const float*)d_in[14];

    unsigned short* Apk = (unsigned short*)d_ws;                                  // 64 MiB
    unsigned short* Bpk = (unsigned short*)((char*)d_ws + (size_t)67108864);      // 16 MiB

    float* out_h = (float*)d_out;
    float* out_c = out_h + (size_t)16384 * 1024;

    pack_a_kernel<<<dim3(16384), dim3(256), 0, stream>>>(input, prev_h, Apk);
    pack_b_kernel<<<dim3(4096), dim3(256), 0, stream>>>(wxi, wxf, wxo, wxu,
                                                        whi, whf, who, whu, Bpk);
    lstm_gemm_kernel<<<dim3(2048), dim3(256), 0, stream>>>(Apk, Bpk, prev_c,
                                                           bi, bf_, bo, bu, out_h, out_c);
}

// Round 13
// 360.189 us; speedup vs baseline: 1.0516x; 1.0516x over previous
//
#include <hip/hip_runtime.h>
#include <hip/hip_bf16.h>
#include <stdint.h>
#include <type_traits>

// B=16384, IN=1024, H=1024, K = IN+H = 2048
// Gate order: 0=i, 1=f, 2=o, 3=u
// ws: A_bf16 [16384][2048] @ 0 (64 MiB); B_bf16 [4][1024][2048] (j-major = W^T) @ 64 MiB

typedef short bf16x8 __attribute__((ext_vector_type(8)));
typedef unsigned short u16x8 __attribute__((ext_vector_type(8)));
typedef float f32x16 __attribute__((ext_vector_type(16)));

__device__ __forceinline__ unsigned short f2bf(float f) {
    union { float f; uint32_t u; } v; v.f = f;
    uint32_t r = v.u + 0x7FFFu + ((v.u >> 16) & 1u);   // RNE
    return (unsigned short)(r >> 16);
}

__device__ __forceinline__ float fsig(float x) { return 1.0f / (1.0f + __expf(-x)); }
__device__ __forceinline__ float ftanh(float x) { return 2.0f * fsig(2.0f * x) - 1.0f; }

// ---------------- pack A: [input | prev_h] -> bf16 [16384][2048] ----------------
__global__ __launch_bounds__(256) void pack_a_kernel(const float* __restrict__ input,
                                                     const float* __restrict__ prev_h,
                                                     unsigned short* __restrict__ Apk) {
    long idx = (long)blockIdx.x * 256 + threadIdx.x;
    long e0 = idx * 8;
    int b = (int)(e0 >> 11);
    int k = (int)(e0 & 2047);
    const float* src = (k < 1024) ? (input + (size_t)b * 1024 + k)
                                  : (prev_h + (size_t)b * 1024 + (k - 1024));
    float4 lo = *(const float4*)src;
    float4 hi = *(const float4*)(src + 4);
    u16x8 o;
    o[0] = f2bf(lo.x); o[1] = f2bf(lo.y); o[2] = f2bf(lo.z); o[3] = f2bf(lo.w);
    o[4] = f2bf(hi.x); o[5] = f2bf(hi.y); o[6] = f2bf(hi.z); o[7] = f2bf(hi.w);
    *(u16x8*)(Apk + e0) = o;
}

// ---------------- pack B: per-gate W^T (j-major) bf16 [4][1024][2048] ----------------
__global__ __launch_bounds__(256) void pack_b_kernel(
        const float* __restrict__ wxi, const float* __restrict__ wxf,
        const float* __restrict__ wxo, const float* __restrict__ wxu,
        const float* __restrict__ whi, const float* __restrict__ whf,
        const float* __restrict__ who, const float* __restrict__ whu,
        unsigned short* __restrict__ Bpk) {
    int idx = blockIdx.x * 256 + threadIdx.x;
    int g  = idx >> 18;
    int r  = idx & 262143;
    int kc = r >> 10;
    int j  = r & 1023;
    const float* wx = (g == 0) ? wxi : (g == 1) ? wxf : (g == 2) ? wxo : wxu;
    const float* wh = (g == 0) ? whi : (g == 1) ? whf : (g == 2) ? who : whu;
    int k0 = kc * 8;
    const float* src = (k0 < 1024) ? (wx + (size_t)k0 * 1024 + j)
                                   : (wh + (size_t)(k0 - 1024) * 1024 + j);
    u16x8 o;
#pragma unroll
    for (int t = 0; t < 8; ++t) o[t] = f2bf(src[(size_t)t * 1024]);
    *(u16x8*)(Bpk + (((size_t)(g * 1024 + j)) << 11) + k0) = o;
}

// ---------------- fused GEMM + LSTM epilogue (32x32x16 MFMA, cross-slice pipeline) ----------------
// grid 1024 = 64 rowTiles x 16 colTiles; block 512 = 8 waves.
// wave w: wr = w>>1 (64-row quarter), wc = w&1 (32-col half of each gate panel).
// Per wave: 64 rows x 32 cols x 4 gates -> acc[2][4] f32x16 (32x32 frags).
// K-loop: BK=32 slices, 4 x 32 KiB LDS buffers, staging lookahead t+3.
// Slice t (ONE free-run segment): {STAGE(t+3); ds_read frags(t+1)->nxt (12 b128,
// INDEPENDENT of this slice's MFMAs); 16 MFMA(32x32x16) on cur; vmcnt(4); BAR}.
// No forced lgkm / SGB / setprio: compiler places the lgkm wait for nxt before
// the NEXT slice's first MFMA (after BAR) -> reads drain under the MFMA window.
// Safety: vmcnt(4) at end of slice t drains STAGE(t+1) (issued t-2) -> buf(t+1)
// published by BAR(t) BEFORE its reads issue in slice t+1... (reads of t+1 are
// issued in slice t, and STAGE(t+1) was drained at end of slice t-1, BAR'd). WAR:
// STAGE(t+3) overwrites buf((t-1)&3), whose last reads drained before BAR(t-1).

#define GLL(gp, lp) __builtin_amdgcn_global_load_lds( \
        (__attribute__((address_space(1))) void*)(gp), \
        (__attribute__((address_space(3))) void*)(lp), 16, 0, 0)

#define BAR() do { asm volatile("" ::: "memory"); __builtin_amdgcn_s_barrier(); \
                   asm volatile("" ::: "memory"); } while (0)

__global__ __launch_bounds__(512, 2) void lstm_gemm_kernel(
        const unsigned short* __restrict__ Apk,   // [16384][2048]
        const unsigned short* __restrict__ Bpk,   // [4][1024][2048] j-major
        const float* __restrict__ prev_c,
        const float* __restrict__ bi, const float* __restrict__ bf_,
        const float* __restrict__ bo, const float* __restrict__ bu,
        float* __restrict__ out_h, float* __restrict__ out_c) {
    __shared__ __align__(16) unsigned char smem[131072];
    const int tid = threadIdx.x;
    const int w = tid >> 6, l = tid & 63;
    const int l31 = l & 31, l5 = l >> 5;
    const int wr = w >> 1, wc = w & 1;

    // XCD-aware bijective swizzle (nwg=1024 % 8 == 0)
    const int bid = blockIdx.x;
    const int sw = ((bid & 7) << 7) + (bid >> 3);
    const int tileRow = sw & 63, tileCol = sw >> 6;
    const int rowBase = tileRow * 256;
    const int jBase = tileCol * 64;

    // fragment read offsets; swizzle key = (row>>1)&3 = (l31>>1)&3 (lane-only)
    const int key = (l31 >> 1) & 3;
    int aoff[2][2], boff[4][2];
#pragma unroll
    for (int m = 0; m < 2; ++m)
#pragma unroll
        for (int ks = 0; ks < 2; ++ks)
            aoff[m][ks] = (wr * 64 + m * 32 + l31) * 64 + ((ks * 2 + l5) ^ key) * 16;
#pragma unroll
    for (int g = 0; g < 4; ++g)
#pragma unroll
        for (int ks = 0; ks < 2; ++ks)
            boff[g][ks] = 16384 + (g * 64 + wc * 32 + l31) * 64 + ((ks * 2 + l5) ^ key) * 16;

    // staging: per-lane pre-swizzled sources; wave-uniform LDS dests
    const int rloc = tid >> 2;                        // 0..127
    const int sigS = ((l & 3) ^ ((l >> 3) & 3)) * 8;  // source element offset
    const unsigned short* aS0 = Apk + (size_t)(rowBase +   0 + rloc) * 2048 + sigS;
    const unsigned short* aS1 = Apk + (size_t)(rowBase + 128 + rloc) * 2048 + sigS;
    const unsigned short* bS0 = Bpk + (((size_t)(((rloc >> 6) + 0) * 1024 + jBase + (rloc & 63))) << 11) + sigS;
    const unsigned short* bS1 = Bpk + (((size_t)(((rloc >> 6) + 2) * 1024 + jBase + (rloc & 63))) << 11) + sigS;
    const int wB = w * 1024;

#define STAGE4(T) do { const int _bb = ((T) & 3) * 32768; \
        GLL(aS0 + (size_t)(T) * 32, smem + _bb +     0 + wB); \
        GLL(aS1 + (size_t)(T) * 32, smem + _bb +  8192 + wB); \
        GLL(bS0 + (size_t)(T) * 32, smem + _bb + 16384 + wB); \
        GLL(bS1 + (size_t)(T) * 32, smem + _bb + 24576 + wB); } while (0)

    f32x16 acc[2][4];
#pragma unroll
    for (int m = 0; m < 2; ++m)
#pragma unroll
        for (int g = 0; g < 4; ++g)
#pragma unroll
            for (int q = 0; q < 16; ++q) acc[m][g][q] = 0.f;

    bf16x8 aE[4], bE[8], aO[4], bO[8];   // frag dbuf: a[m*2+ks], b[g*2+ks]

    auto ldfr = [&](int t, bf16x8 (&da)[4], bf16x8 (&db)[8]) {
        const int bt = (t & 3) * 32768;
#pragma unroll
        for (int m = 0; m < 2; ++m)
#pragma unroll
            for (int ks = 0; ks < 2; ++ks)
                da[m * 2 + ks] = *(const bf16x8*)(smem + bt + aoff[m][ks]);
#pragma unroll
        for (int g = 0; g < 4; ++g)
#pragma unroll
            for (int ks = 0; ks < 2; ++ks)
                db[g * 2 + ks] = *(const bf16x8*)(smem + bt + boff[g][ks]);
    };

    // prologue: stage slices 0,1,2; drain 0 AND 1 (reads of frags(1) occur in slice 0)
    STAGE4(0); STAGE4(1); STAGE4(2);
    asm volatile("s_waitcnt vmcnt(4)" ::: "memory");
    BAR();
    ldfr(0, aE, bE);

    auto slice = [&](int t, auto vnc, auto stgc, auto nxtc,
                     bf16x8 (&ca)[4], bf16x8 (&cb)[8],
                     bf16x8 (&na)[4], bf16x8 (&nb)[8]) {
        constexpr int VN = decltype(vnc)::value;   // 4 steady; 0 drain; -1 none
        constexpr bool STG = decltype(stgc)::value;
        constexpr bool NXT = decltype(nxtc)::value;
        if constexpr (STG) STAGE4(t + 3);
        if constexpr (NXT) ldfr(t + 1, na, nb);    // independent of MFMAs below
#pragma unroll
        for (int ks = 0; ks < 2; ++ks)
#pragma unroll
            for (int m = 0; m < 2; ++m)
#pragma unroll
                for (int g = 0; g < 4; ++g)
                    acc[m][g] = __builtin_amdgcn_mfma_f32_32x32x16_bf16(
                        ca[m * 2 + ks], cb[g * 2 + ks], acc[m][g], 0, 0, 0);
        if constexpr (VN == 4)      asm volatile("s_waitcnt vmcnt(4)" ::: "memory");
        else if constexpr (VN == 0) asm volatile("s_waitcnt vmcnt(0)" ::: "memory");
        if constexpr (VN >= 0) BAR();
    };

    using c4 = std::integral_constant<int, 4>;
    using c0 = std::integral_constant<int, 0>;
    using cm = std::integral_constant<int, -1>;
    using bT = std::integral_constant<bool, true>;
    using bF = std::integral_constant<bool, false>;

#pragma unroll 1
    for (int t = 0; t < 60; t += 2) {
        slice(t,     c4{}, bT{}, bT{}, aE, bE, aO, bO);
        slice(t + 1, c4{}, bT{}, bT{}, aO, bO, aE, bE);
    }
    slice(60, c4{}, bT{}, bT{}, aE, bE, aO, bO);   // stages 63
    slice(61, c0{}, bF{}, bT{}, aO, bO, aE, bE);   // drain 63's loads
    slice(62, cm{}, bF{}, bT{}, aE, bE, aO, bO);   // reads frags(63); no bar needed
    slice(63, cm{}, bF{}, bF{}, aO, bO, aE, bE);

    // ---- epilogue: lane-local; C/D: col=l31, row=(q&3)+8*(q>>2)+4*l5 ----
    const int colIdx = jBase + wc * 32 + l31;
    const float vbi = bi[colIdx], vbf = bf_[colIdx], vbo = bo[colIdx], vbu = bu[colIdx];
    const int rowB = rowBase + wr * 64 + 4 * l5;
#pragma unroll
    for (int m = 0; m < 2; ++m) {
#pragma unroll
        for (int q = 0; q < 16; ++q) {
            const int row = rowB + m * 32 + (q & 3) + 8 * (q >> 2);
            const size_t idx = (size_t)row * 1024 + colIdx;
            float zi = acc[m][0][q] + vbi;
            float zf = acc[m][1][q] + vbf;
            float zo = acc[m][2][q] + vbo;
            float zu = acc[m][3][q] + vbu;
            float iv = fsig(zi), fv = fsig(zf), ov = fsig(zo), uv = ftanh(zu);
            float cv = fv * prev_c[idx] + iv * uv;
            out_c[idx] = cv;
            out_h[idx] = ov * ftanh(cv);
        }
    }
#undef STAGE4
}

extern "C" void kernel_launch(void* const* d_in, const int* in_sizes, int n_in,
                              void* d_out, int out_size, void* d_ws, size_t ws_size,
                              hipStream_t stream) {
    const float* input  = (const float*)d_in[0];
    const float* prev_h = (const float*)d_in[1];
    const float* prev_c = (const float*)d_in[2];
    const float* wxi = (const float*)d_in[3];
    const float* whi = (const float*)d_in[4];
    const float* wxf = (const float*)d_in[5];
    const float* whf = (const float*)d_in[6];
    const float* wxu = (const float*)d_in[7];
    const float* whu = (const float*)d_in[8];
    const float* wxo = (const float*)d_in[9];
    const float* who = (const float*)d_in[10];
    const float* bi  = (const float*)d_in[11];
    const float* bf_ = (const float*)d_in[12];
    const float* bo  = (const float*)d_in[13];
    const float* bu  = (const float*)d_in[14];

    unsigned short* Apk = (unsigned short*)d_ws;                                  // 64 MiB
    unsigned short* Bpk = (unsigned short*)((char*)d_ws + (size_t)67108864);      // 16 MiB

    float* out_h = (float*)d_out;
    float* out_c = out_h + (size_t)16384 * 1024;

    pack_a_kernel<<<dim3(16384), dim3(256), 0, stream>>>(input, prev_h, Apk);
    pack_b_kernel<<<dim3(4096), dim3(256), 0, stream>>>(wxi, wxf, wxo, wxu,
                                                        whi, whf, who, whu, Bpk);
    lstm_gemm_kernel<<<dim3(1024), dim3(512), 0, stream>>>(Apk, Bpk, prev_c,
                                                           bi, bf_, bo, bu, out_h, out_c);
}